// Round 1
// baseline (5461.751 us; speedup 1.0000x reference)
//
#include <hip/hip_runtime.h>
#include <math.h>

// Problem constants (from reference)
#define BS    8
#define NE    4800
#define NN    4981
#define CIN   3
#define HD    128      // H
#define DBLK  6        // D processor blocks
#define NEDGE 153600   // BS*EPG
#define NTOT  38400    // BS*NE (graph nodes)
#define NMESH (BS*NN)  // 39848 mesh rows

__device__ __forceinline__ float lrelu(float x) { return x >= 0.0f ? x : 0.2f * x; }

// ---------------------------------------------------------------------------
// K0: hv0 = ln(mlp(enc_clnb_row, enc_ew1..3), enc_elng, enc_elnb)
// The conv encoder + LayerNorm(axis of size 1) collapses exactly to enc_clnb.
// ---------------------------------------------------------------------------
__global__ __launch_bounds__(128)
void enc_const_kernel(const float* __restrict__ clnb,
                      const float* __restrict__ ew1, const float* __restrict__ eb1,
                      const float* __restrict__ ew2, const float* __restrict__ eb2,
                      const float* __restrict__ ew3,
                      const float* __restrict__ g, const float* __restrict__ b,
                      float* __restrict__ hv0) {
    __shared__ float s1[HD], s2[HD], s3[HD];
    int j = threadIdx.x;
    float a = eb1[j];
    for (int c = 0; c < CIN; ++c) a += clnb[c] * ew1[c * HD + j];
    s1[j] = lrelu(a);
    __syncthreads();
    a = eb2[j];
    for (int k = 0; k < HD; ++k) a += s1[k] * ew2[k * HD + j];
    s2[j] = lrelu(a);
    __syncthreads();
    a = 0.0f;
    for (int k = 0; k < HD; ++k) a += s2[k] * ew3[k * HD + j];
    s3[j] = a;
    __syncthreads();
    float m = 0.0f;
    for (int k = 0; k < HD; ++k) m += s3[k];
    m *= (1.0f / HD);
    float v = 0.0f;
    for (int k = 0; k < HD; ++k) { float d = s3[k] - m; v += d * d; }
    v *= (1.0f / HD);
    float rs = 1.0f / sqrtf(v + 1e-5f);
    hv0[j] = (s3[j] - m) * rs * g[j] + b[j];
}

// Broadcast hv0 to all NTOT node rows
__global__ __launch_bounds__(256)
void init_h_kernel(float* __restrict__ h, const float* __restrict__ hv0, int n4) {
    __shared__ float4 v[HD / 4];
    if (threadIdx.x < HD / 4) v[threadIdx.x] = ((const float4*)hv0)[threadIdx.x];
    __syncthreads();
    for (int i = blockIdx.x * blockDim.x + threadIdx.x; i < n4; i += gridDim.x * blockDim.x)
        ((float4*)h)[i] = v[i & (HD / 4 - 1)];
}

// ---------------------------------------------------------------------------
// Fused GraphNet MLP tile kernel. MODE 0 = edge (gather h[dest],h[src], atomic
// scatter-add to aggr[dest]); MODE 1 = node (h[n], aggr[n], write hnext[n]).
// Tile = 64 rows x 128 outputs, 256 threads, each thread 8 rows x 4 cols.
// ---------------------------------------------------------------------------
__device__ __forceinline__ void kpass(const float (*A)[HD + 4], const float* __restrict__ W,
                                      int rowoff, int tid, int eg, int j0,
                                      float acc[8][4], float (*Bs)[HD + 4]) {
    for (int kb = 0; kb < 8; ++kb) {
        __syncthreads();
        #pragma unroll
        for (int t = 0; t < 2; ++t) {
            int idx = tid + t * 256;
            int kr = idx >> 5, c4 = (idx & 31) << 2;
            *(float4*)(&Bs[kr][c4]) =
                *(const float4*)(W + (size_t)(rowoff + kb * 16 + kr) * HD + c4);
        }
        __syncthreads();
        #pragma unroll
        for (int kk = 0; kk < 16; kk += 4) {
            float4 bv0 = *(const float4*)(&Bs[kk + 0][j0]);
            float4 bv1 = *(const float4*)(&Bs[kk + 1][j0]);
            float4 bv2 = *(const float4*)(&Bs[kk + 2][j0]);
            float4 bv3 = *(const float4*)(&Bs[kk + 3][j0]);
            #pragma unroll
            for (int i = 0; i < 8; ++i) {
                float4 av = *(const float4*)(&A[eg * 8 + i][kb * 16 + kk]);
                acc[i][0] += av.x * bv0.x + av.y * bv1.x + av.z * bv2.x + av.w * bv3.x;
                acc[i][1] += av.x * bv0.y + av.y * bv1.y + av.z * bv2.y + av.w * bv3.y;
                acc[i][2] += av.x * bv0.z + av.y * bv1.z + av.z * bv2.z + av.w * bv3.z;
                acc[i][3] += av.x * bv0.w + av.y * bv1.w + av.z * bv2.w + av.w * bv3.w;
            }
        }
    }
}

template <int MODE>
__global__ __launch_bounds__(256)
void gn_kernel(const float* __restrict__ hcur, const float* __restrict__ aggr_in,
               const int* __restrict__ dest, const int* __restrict__ src,
               const float* __restrict__ w1, const float* __restrict__ b1,
               const float* __restrict__ w2, const float* __restrict__ b2,
               const float* __restrict__ w3,
               const float* __restrict__ g, const float* __restrict__ bln,
               float* __restrict__ out) {
    __shared__ float As1[64][HD + 4];
    __shared__ float As2[64][HD + 4];
    __shared__ float Bs[16][HD + 4];
    __shared__ float red[64][4][2];
    __shared__ float mrs[64][2];
    __shared__ int dS[64], sS[64];

    const int tid = threadIdx.x;
    const int base = blockIdx.x * 64;
    const int jg = tid & 31, eg = tid >> 5;
    const int j0 = jg * 4;

    if (MODE == 0) {
        if (tid < 64) dS[tid] = dest[base + tid];
        else if (tid < 128) sS[tid - 64] = src[base + tid - 64];
    }
    __syncthreads();

    // Load A tiles (row gather, float4)
    #pragma unroll
    for (int t = 0; t < 8; ++t) {
        int idx = tid + t * 256;           // 0..2047
        int r = idx >> 5, c4 = (idx & 31) << 2;
        if (MODE == 0) {
            size_t r1 = (size_t)dS[r] * HD, r2 = (size_t)sS[r] * HD;
            *(float4*)(&As1[r][c4]) = *(const float4*)(hcur + r1 + c4);
            *(float4*)(&As2[r][c4]) = *(const float4*)(hcur + r2 + c4);
        } else {
            size_t rr = (size_t)(base + r) * HD;
            *(float4*)(&As1[r][c4]) = *(const float4*)(hcur + rr + c4);
            *(float4*)(&As2[r][c4]) = *(const float4*)(aggr_in + rr + c4);
        }
    }
    __syncthreads();

    float acc[8][4];

    // ---- Layer 1: K = 256 (concat [As1 | As2]), bias b1, lrelu
    {
        float4 bb = *(const float4*)(b1 + j0);
        #pragma unroll
        for (int i = 0; i < 8; ++i) { acc[i][0] = bb.x; acc[i][1] = bb.y; acc[i][2] = bb.z; acc[i][3] = bb.w; }
    }
    kpass(As1, w1, 0, tid, eg, j0, acc, Bs);
    kpass(As2, w1, HD, tid, eg, j0, acc, Bs);
    __syncthreads();
    #pragma unroll
    for (int i = 0; i < 8; ++i) {
        float4 v = make_float4(lrelu(acc[i][0]), lrelu(acc[i][1]), lrelu(acc[i][2]), lrelu(acc[i][3]));
        *(float4*)(&As1[eg * 8 + i][j0]) = v;
    }
    __syncthreads();

    // ---- Layer 2: K = 128, bias b2, lrelu
    {
        float4 bb = *(const float4*)(b2 + j0);
        #pragma unroll
        for (int i = 0; i < 8; ++i) { acc[i][0] = bb.x; acc[i][1] = bb.y; acc[i][2] = bb.z; acc[i][3] = bb.w; }
    }
    kpass(As1, w2, 0, tid, eg, j0, acc, Bs);
    __syncthreads();
    #pragma unroll
    for (int i = 0; i < 8; ++i) {
        float4 v = make_float4(lrelu(acc[i][0]), lrelu(acc[i][1]), lrelu(acc[i][2]), lrelu(acc[i][3]));
        *(float4*)(&As2[eg * 8 + i][j0]) = v;
    }
    __syncthreads();

    // ---- Layer 3: K = 128, no bias, no activation
    #pragma unroll
    for (int i = 0; i < 8; ++i) { acc[i][0] = 0.f; acc[i][1] = 0.f; acc[i][2] = 0.f; acc[i][3] = 0.f; }
    kpass(As2, w3, 0, tid, eg, j0, acc, Bs);

    // ---- LayerNorm per row over 128 outputs
    __syncthreads();
    #pragma unroll
    for (int i = 0; i < 8; ++i)
        *(float4*)(&As1[eg * 8 + i][j0]) = make_float4(acc[i][0], acc[i][1], acc[i][2], acc[i][3]);
    __syncthreads();
    {
        int e = tid >> 2, part = tid & 3;
        float s = 0.f, q = 0.f;
        #pragma unroll
        for (int c = 0; c < 8; ++c) {
            float4 v = *(const float4*)(&As1[e][part * 32 + c * 4]);
            s += v.x + v.y + v.z + v.w;
            q += v.x * v.x + v.y * v.y + v.z * v.z + v.w * v.w;
        }
        red[e][part][0] = s; red[e][part][1] = q;
    }
    __syncthreads();
    if (tid < 64) {
        float s = red[tid][0][0] + red[tid][1][0] + red[tid][2][0] + red[tid][3][0];
        float q = red[tid][0][1] + red[tid][1][1] + red[tid][2][1] + red[tid][3][1];
        float m = s * (1.0f / HD);
        float var = q * (1.0f / HD) - m * m;
        mrs[tid][0] = m;
        mrs[tid][1] = 1.0f / sqrtf(var + 1e-5f);
    }
    __syncthreads();

    float4 gv = *(const float4*)(g + j0);
    float4 bv = *(const float4*)(bln + j0);
    #pragma unroll
    for (int i = 0; i < 8; ++i) {
        int e = eg * 8 + i;
        float m = mrs[e][0], rs = mrs[e][1];
        float v0 = (acc[i][0] - m) * rs * gv.x + bv.x;
        float v1 = (acc[i][1] - m) * rs * gv.y + bv.y;
        float v2 = (acc[i][2] - m) * rs * gv.z + bv.z;
        float v3 = (acc[i][3] - m) * rs * gv.w + bv.w;
        if (MODE == 0) {
            float* p = out + (size_t)dS[e] * HD + j0;
            atomicAdd(p + 0, v0); atomicAdd(p + 1, v1);
            atomicAdd(p + 2, v2); atomicAdd(p + 3, v3);
        } else {
            *(float4*)(out + (size_t)(base + e) * HD + j0) = make_float4(v0, v1, v2, v3);
        }
    }
}

// ---------------------------------------------------------------------------
// Decoder stage 1: per-channel upsample 1->4 + LN(4) + scatter-add to mesh
// ---------------------------------------------------------------------------
__global__ __launch_bounds__(128)
void dec_up_kernel(const float* __restrict__ h, const int* __restrict__ conn,
                   const float* __restrict__ uw1, const float* __restrict__ ub1,
                   const float* __restrict__ uw2, const float* __restrict__ ub2,
                   const float* __restrict__ uw3,
                   const float* __restrict__ ulng, const float* __restrict__ ulnb,
                   float* __restrict__ outn) {
    int n = blockIdx.x;            // 0..BS*NE-1
    int b = n / NE, e = n - b * NE;
    int c = threadIdx.x;
    __shared__ int nd[4];
    if (c < 4) nd[c] = conn[e * 4 + c];
    float s = h[(size_t)n * HD + c];
    float u1[4], u2[4], u3[4];
    #pragma unroll
    for (int o = 0; o < 4; ++o) u1[o] = lrelu(s * uw1[c * 4 + o] + ub1[c * 4 + o]);
    #pragma unroll
    for (int o = 0; o < 4; ++o) {
        float a = ub2[c * 4 + o];
        #pragma unroll
        for (int i = 0; i < 4; ++i) a += u1[i] * uw2[c * 16 + i * 4 + o];
        u2[o] = lrelu(a);
    }
    #pragma unroll
    for (int o = 0; o < 4; ++o) {
        float a = 0.f;
        #pragma unroll
        for (int i = 0; i < 4; ++i) a += u2[i] * uw3[c * 16 + i * 4 + o];
        u3[o] = a;
    }
    float m = 0.25f * (u3[0] + u3[1] + u3[2] + u3[3]);
    float var = 0.f;
    #pragma unroll
    for (int o = 0; o < 4; ++o) { float d = u3[o] - m; var += d * d; }
    var *= 0.25f;
    float rs = 1.0f / sqrtf(var + 1e-5f);
    __syncthreads();
    #pragma unroll
    for (int o = 0; o < 4; ++o) {
        float val = (u3[o] - m) * rs * ulng[c * 4 + o] + ulnb[c * 4 + o];
        atomicAdd(&outn[((size_t)b * NN + nd[o]) * HD + c], val);
    }
}

// ---------------------------------------------------------------------------
// Decoder stage 2: per mesh row H->3->3->3, one wave per row
// ---------------------------------------------------------------------------
__global__ __launch_bounds__(256)
void dec_out_kernel(const float* __restrict__ outn,
                    const float* __restrict__ cw1, const float* __restrict__ cb1,
                    const float* __restrict__ cw2, const float* __restrict__ cb2,
                    const float* __restrict__ cw3,
                    float* __restrict__ o, int nrows) {
    int r = blockIdx.x * 4 + (threadIdx.x >> 6);
    if (r >= nrows) return;
    int lane = threadIdx.x & 63;
    float v1 = outn[(size_t)r * HD + lane];
    float v2 = outn[(size_t)r * HD + 64 + lane];
    float s[3];
    #pragma unroll
    for (int c = 0; c < 3; ++c)
        s[c] = v1 * cw1[lane * 3 + c] + v2 * cw1[(lane + 64) * 3 + c];
    #pragma unroll
    for (int off = 32; off >= 1; off >>= 1) {
        s[0] += __shfl_down(s[0], off);
        s[1] += __shfl_down(s[1], off);
        s[2] += __shfl_down(s[2], off);
    }
    if (lane == 0) {
        float t1[3], t2[3];
        #pragma unroll
        for (int c = 0; c < 3; ++c) t1[c] = lrelu(s[c] + cb1[c]);
        #pragma unroll
        for (int c = 0; c < 3; ++c) {
            float a = cb2[c];
            #pragma unroll
            for (int k = 0; k < 3; ++k) a += t1[k] * cw2[k * 3 + c];
            t2[c] = lrelu(a);
        }
        #pragma unroll
        for (int c = 0; c < 3; ++c) {
            float a = 0.f;
            #pragma unroll
            for (int k = 0; k < 3; ++k) a += t2[k] * cw3[k * 3 + c];
            o[(size_t)r * 3 + c] = a;
        }
    }
}

// ---------------------------------------------------------------------------
extern "C" void kernel_launch(void* const* d_in, const int* in_sizes, int n_in,
                              void* d_out, int out_size, void* d_ws, size_t ws_size,
                              hipStream_t stream) {
    // input order per setup_inputs
    const int* elem_conn = (const int*)d_in[1];
    const int* edge_index = (const int*)d_in[2];
    const int* e_src = edge_index;          // row 0
    const int* e_dst = edge_index + NEDGE;  // row 1
    const float* enc_clnb = (const float*)d_in[9];
    const float* enc_ew1 = (const float*)d_in[10];
    const float* enc_eb1 = (const float*)d_in[11];
    const float* enc_ew2 = (const float*)d_in[12];
    const float* enc_eb2 = (const float*)d_in[13];
    const float* enc_ew3 = (const float*)d_in[14];
    const float* enc_elng = (const float*)d_in[15];
    const float* enc_elnb = (const float*)d_in[16];
    const float* p_ew1 = (const float*)d_in[17];
    const float* p_eb1 = (const float*)d_in[18];
    const float* p_ew2 = (const float*)d_in[19];
    const float* p_eb2 = (const float*)d_in[20];
    const float* p_ew3 = (const float*)d_in[21];
    const float* p_elng = (const float*)d_in[22];
    const float* p_elnb = (const float*)d_in[23];
    const float* p_nw1 = (const float*)d_in[24];
    const float* p_nb1 = (const float*)d_in[25];
    const float* p_nw2 = (const float*)d_in[26];
    const float* p_nb2 = (const float*)d_in[27];
    const float* p_nw3 = (const float*)d_in[28];
    const float* p_nlng = (const float*)d_in[29];
    const float* p_nlnb = (const float*)d_in[30];
    const float* dec_uw1 = (const float*)d_in[31];
    const float* dec_ub1 = (const float*)d_in[32];
    const float* dec_uw2 = (const float*)d_in[33];
    const float* dec_ub2 = (const float*)d_in[34];
    const float* dec_uw3 = (const float*)d_in[35];
    const float* dec_ulng = (const float*)d_in[36];
    const float* dec_ulnb = (const float*)d_in[37];
    const float* dec_cw1 = (const float*)d_in[38];
    const float* dec_cb1 = (const float*)d_in[39];
    const float* dec_cw2 = (const float*)d_in[40];
    const float* dec_cb2 = (const float*)d_in[41];
    const float* dec_cw3 = (const float*)d_in[42];

    // workspace layout (floats): hA | hB | aggr | hv0 ; outn aliases hB (+spill
    // into aggr) after the processor is done. ~59 MB total.
    float* hA = (float*)d_ws;
    float* hB = hA + (size_t)NTOT * HD;
    float* aggr = hB + (size_t)NTOT * HD;
    float* hv0 = aggr + (size_t)NTOT * HD;
    float* outn = hB;  // BS*NN*HD floats, overlaps hB+aggr (both dead by then)

    enc_const_kernel<<<1, 128, 0, stream>>>(enc_clnb, enc_ew1, enc_eb1, enc_ew2,
                                            enc_eb2, enc_ew3, enc_elng, enc_elnb, hv0);
    init_h_kernel<<<2400, 256, 0, stream>>>(hA, hv0, NTOT * HD / 4);

    for (int d = 0; d < DBLK; ++d) {
        float* cur = (d & 1) ? hB : hA;
        float* nxt = (d & 1) ? hA : hB;
        hipMemsetAsync(aggr, 0, (size_t)NTOT * HD * sizeof(float), stream);
        gn_kernel<0><<<NEDGE / 64, 256, 0, stream>>>(
            cur, nullptr, e_dst, e_src,
            p_ew1 + (size_t)d * 2 * HD * HD, p_eb1 + (size_t)d * HD,
            p_ew2 + (size_t)d * HD * HD, p_eb2 + (size_t)d * HD,
            p_ew3 + (size_t)d * HD * HD,
            p_elng + (size_t)d * HD, p_elnb + (size_t)d * HD, aggr);
        gn_kernel<1><<<NTOT / 64, 256, 0, stream>>>(
            cur, aggr, nullptr, nullptr,
            p_nw1 + (size_t)d * 2 * HD * HD, p_nb1 + (size_t)d * HD,
            p_nw2 + (size_t)d * HD * HD, p_nb2 + (size_t)d * HD,
            p_nw3 + (size_t)d * HD * HD,
            p_nlng + (size_t)d * HD, p_nlnb + (size_t)d * HD, nxt);
    }
    // after d=5, result is in hA
    hipMemsetAsync(outn, 0, (size_t)NMESH * HD * sizeof(float), stream);
    dec_up_kernel<<<BS * NE, 128, 0, stream>>>(hA, elem_conn, dec_uw1, dec_ub1,
                                               dec_uw2, dec_ub2, dec_uw3,
                                               dec_ulng, dec_ulnb, outn);
    dec_out_kernel<<<(NMESH + 3) / 4, 256, 0, stream>>>(outn, dec_cw1, dec_cb1,
                                                        dec_cw2, dec_cb2, dec_cw3,
                                                        (float*)d_out, NMESH);
}

// Round 2
// 933.260 us; speedup vs baseline: 5.8523x; 5.8523x over previous
//
#include <hip/hip_runtime.h>
#include <math.h>

// Problem constants (from reference)
#define BS    8
#define NE    4800
#define NN    4981
#define CIN   3
#define HD    128      // H
#define DBLK  6        // D processor blocks
#define NEDGE 153600   // BS*EPG
#define NTOT  38400    // BS*NE (graph nodes)
#define NMESH (BS*NN)  // 39848 mesh rows

typedef _Float16 f16;
typedef _Float16 f16x8 __attribute__((ext_vector_type(8)));
typedef float f32x4 __attribute__((ext_vector_type(4)));

__device__ __forceinline__ float lrelu(float x) { return x >= 0.0f ? x : 0.2f * x; }

// ---------------------------------------------------------------------------
// K0: hv0 = ln(mlp(enc_clnb_row, enc_ew1..3), enc_elng, enc_elnb)
// The conv encoder + LayerNorm over an axis of size 1 collapses exactly to
// enc_clnb (x and elem_conn are dead for the encoder output).
// ---------------------------------------------------------------------------
__global__ __launch_bounds__(128)
void enc_const_kernel(const float* __restrict__ clnb,
                      const float* __restrict__ ew1, const float* __restrict__ eb1,
                      const float* __restrict__ ew2, const float* __restrict__ eb2,
                      const float* __restrict__ ew3,
                      const float* __restrict__ g, const float* __restrict__ b,
                      float* __restrict__ hv0) {
    __shared__ float s1[HD], s2[HD], s3[HD];
    int j = threadIdx.x;
    float a = eb1[j];
    for (int c = 0; c < CIN; ++c) a += clnb[c] * ew1[c * HD + j];
    s1[j] = lrelu(a);
    __syncthreads();
    a = eb2[j];
    for (int k = 0; k < HD; ++k) a += s1[k] * ew2[k * HD + j];
    s2[j] = lrelu(a);
    __syncthreads();
    a = 0.0f;
    for (int k = 0; k < HD; ++k) a += s2[k] * ew3[k * HD + j];
    s3[j] = a;
    __syncthreads();
    float m = 0.0f;
    for (int k = 0; k < HD; ++k) m += s3[k];
    m *= (1.0f / HD);
    float v = 0.0f;
    for (int k = 0; k < HD; ++k) { float d = s3[k] - m; v += d * d; }
    v *= (1.0f / HD);
    float rs = 1.0f / sqrtf(v + 1e-5f);
    hv0[j] = (s3[j] - m) * rs * g[j] + b[j];
}

// Broadcast hv0 (fp32) to all NTOT node rows as f16
__global__ __launch_bounds__(256)
void init_h16_kernel(f16* __restrict__ h, const float* __restrict__ hv0, int n8) {
    __shared__ f16 v[HD];
    if (threadIdx.x < HD) v[threadIdx.x] = (f16)hv0[threadIdx.x];
    __syncthreads();
    for (int i = blockIdx.x * blockDim.x + threadIdx.x; i < n8; i += gridDim.x * blockDim.x)
        ((uint4*)h)[i] = ((const uint4*)v)[i & 15];
}

// ---------------------------------------------------------------------------
// Convert + transpose processor weights to f16 Wt[n][k] layout.
// 48 output matrices of 128x128: per d: eW1a,eW1b,eW2,eW3,nW1a,nW1b,nW2,nW3
// ---------------------------------------------------------------------------
__global__ __launch_bounds__(256)
void conv_weights_kernel(const float* __restrict__ ew1, const float* __restrict__ ew2,
                         const float* __restrict__ ew3,
                         const float* __restrict__ nw1, const float* __restrict__ nw2,
                         const float* __restrict__ nw3, f16* __restrict__ wbuf) {
    int b = blockIdx.x;        // 0..47
    int d = b >> 3, m = b & 7;
    const float* src;
    switch (m) {
        case 0: src = ew1 + (size_t)d * 2 * HD * HD; break;
        case 1: src = ew1 + (size_t)d * 2 * HD * HD + HD * HD; break;
        case 2: src = ew2 + (size_t)d * HD * HD; break;
        case 3: src = ew3 + (size_t)d * HD * HD; break;
        case 4: src = nw1 + (size_t)d * 2 * HD * HD; break;
        case 5: src = nw1 + (size_t)d * 2 * HD * HD + HD * HD; break;
        case 6: src = nw2 + (size_t)d * HD * HD; break;
        default: src = nw3 + (size_t)d * HD * HD; break;
    }
    f16* out = wbuf + (size_t)b * HD * HD;
    for (int idx = threadIdx.x; idx < HD * HD; idx += 256) {
        int n = idx >> 7, k = idx & 127;
        out[idx] = (f16)src[k * HD + n];   // Wt[n][k] = W[k][n]
    }
}

// ---------------------------------------------------------------------------
// Fused GraphNet MLP tile kernel on MFMA (fp16 in, fp32 accumulate).
// MODE 0 = edge: A1=h[dest], A2=h[src]; LN output atomically scattered to aggr.
// MODE 1 = node: A1=h[row],  A2=aggr[row] (fp32->f16); LN output -> h_out f16.
// Tile 64 rows x 128 outputs, 256 threads = 4 waves; wave w: rows (w>>1)*32..+31,
// cols (w&1)*64..+63 as 2x4 grid of 16x16 MFMA tiles.
// Layouts (guide-verified, dtype-independent): A[m=lane&15][k=quad*8+j],
// B[k=quad*8+j][n=lane&15], C/D col=lane&15 row=quad*4+reg.
// LDS: As1/As2 64x136 f16 (pad 8 -> 2-way bank alias = free), Bt 128x136 f16,
// Bt reused as fp32 [64][132] LN scratch. Total 72.7 KB -> 2 blocks/CU.
// ---------------------------------------------------------------------------
__device__ __forceinline__ void gemm_k128(const f16 (*A)[HD + 8], const f16* __restrict__ Wg,
                                          f16 (*Bt)[HD + 8], int tid, int rt_base,
                                          int ct_base, int ln, int quad, f32x4 acc[2][4]) {
    __syncthreads();    // previous Bt readers done; A-writes visible after next barrier
    #pragma unroll
    for (int t = 0; t < 8; ++t) {
        int idx = tid + t * 256;            // 0..2047, 16B chunks of 128x128 f16
        int r = idx >> 4, c = (idx & 15) * 8;
        *(uint4*)(&Bt[r][c]) = *(const uint4*)(Wg + r * HD + c);
    }
    __syncthreads();
    #pragma unroll
    for (int ks = 0; ks < 4; ++ks) {
        int kb = ks * 32 + quad * 8;
        f16x8 a0 = *(const f16x8*)(&A[rt_base + ln][kb]);
        f16x8 a1 = *(const f16x8*)(&A[rt_base + 16 + ln][kb]);
        #pragma unroll
        for (int c = 0; c < 4; ++c) {
            f16x8 b = *(const f16x8*)(&Bt[ct_base + c * 16 + ln][kb]);
            acc[0][c] = __builtin_amdgcn_mfma_f32_16x16x32_f16(a0, b, acc[0][c], 0, 0, 0);
            acc[1][c] = __builtin_amdgcn_mfma_f32_16x16x32_f16(a1, b, acc[1][c], 0, 0, 0);
        }
    }
}

template <int MODE>
__global__ __launch_bounds__(256, 2)
void gn_mfma(const f16* __restrict__ h16, const float* __restrict__ aggr_in,
             const int* __restrict__ dest, const int* __restrict__ src,
             const f16* __restrict__ W1a, const f16* __restrict__ W1b,
             const f16* __restrict__ W2, const f16* __restrict__ W3,
             const float* __restrict__ b1, const float* __restrict__ b2,
             const float* __restrict__ g, const float* __restrict__ bln,
             float* __restrict__ aggr_out, f16* __restrict__ h_out) {
    __shared__ __align__(16) f16 As1[64][HD + 8];
    __shared__ __align__(16) f16 As2[64][HD + 8];
    __shared__ __align__(16) f16 Bt[HD][HD + 8];
    __shared__ float red[64][4][2];
    __shared__ float mrs[64][2];
    __shared__ int dS[64], sS[64];

    const int tid = threadIdx.x;
    const int base = blockIdx.x * 64;
    const int wave = tid >> 6;
    const int lane = tid & 63;
    const int ln = lane & 15;
    const int quad = lane >> 4;
    const int rt_base = (wave >> 1) * 32;
    const int ct_base = (wave & 1) * 64;

    if (MODE == 0) {
        if (tid < 64) dS[tid] = dest[base + tid];
        else if (tid < 128) sS[tid - 64] = src[base + tid - 64];
        __syncthreads();
    }

    // ---- Stage A tiles (f16, 16B chunks: 64 rows x 16 chunks = 1024 per tile)
    #pragma unroll
    for (int t = 0; t < 4; ++t) {
        int idx = tid + t * 256;            // 0..1023
        int r = idx >> 4, c = (idx & 15) * 8;
        if (MODE == 0) {
            *(uint4*)(&As1[r][c]) = *(const uint4*)(h16 + (size_t)dS[r] * HD + c);
            *(uint4*)(&As2[r][c]) = *(const uint4*)(h16 + (size_t)sS[r] * HD + c);
        } else {
            *(uint4*)(&As1[r][c]) = *(const uint4*)(h16 + (size_t)(base + r) * HD + c);
            const float* p = aggr_in + (size_t)(base + r) * HD + c;
            float4 u = *(const float4*)p;
            float4 v = *(const float4*)(p + 4);
            f16x8 hv;
            hv[0] = (f16)u.x; hv[1] = (f16)u.y; hv[2] = (f16)u.z; hv[3] = (f16)u.w;
            hv[4] = (f16)v.x; hv[5] = (f16)v.y; hv[6] = (f16)v.z; hv[7] = (f16)v.w;
            *(f16x8*)(&As2[r][c]) = hv;
        }
    }
    // (visibility of A-writes is covered by gemm_k128's internal barriers)

    f32x4 acc[2][4];

    // ---- Layer 1: K=256 split over [As1 | As2], bias b1, lrelu
    #pragma unroll
    for (int c = 0; c < 4; ++c) {
        float bj = b1[ct_base + c * 16 + ln];
        f32x4 bb = {bj, bj, bj, bj};
        acc[0][c] = bb; acc[1][c] = bb;
    }
    gemm_k128(As1, W1a, Bt, tid, rt_base, ct_base, ln, quad, acc);
    gemm_k128(As2, W1b, Bt, tid, rt_base, ct_base, ln, quad, acc);
    __syncthreads();          // all waves done reading As1/As2
    #pragma unroll
    for (int i = 0; i < 2; ++i)
        #pragma unroll
        for (int c = 0; c < 4; ++c)
            #pragma unroll
            for (int r = 0; r < 4; ++r) {
                int row = rt_base + i * 16 + quad * 4 + r;
                int col = ct_base + c * 16 + ln;
                As1[row][col] = (f16)lrelu(acc[i][c][r]);
            }

    // ---- Layer 2: K=128 over As1, bias b2, lrelu
    #pragma unroll
    for (int c = 0; c < 4; ++c) {
        float bj = b2[ct_base + c * 16 + ln];
        f32x4 bb = {bj, bj, bj, bj};
        acc[0][c] = bb; acc[1][c] = bb;
    }
    gemm_k128(As1, W2, Bt, tid, rt_base, ct_base, ln, quad, acc);
    __syncthreads();
    #pragma unroll
    for (int i = 0; i < 2; ++i)
        #pragma unroll
        for (int c = 0; c < 4; ++c)
            #pragma unroll
            for (int r = 0; r < 4; ++r) {
                int row = rt_base + i * 16 + quad * 4 + r;
                int col = ct_base + c * 16 + ln;
                As2[row][col] = (f16)lrelu(acc[i][c][r]);
            }

    // ---- Layer 3: K=128 over As2, no bias/activation
    #pragma unroll
    for (int c = 0; c < 4; ++c) {
        f32x4 z = {0.f, 0.f, 0.f, 0.f};
        acc[0][c] = z; acc[1][c] = z;
    }
    gemm_k128(As2, W3, Bt, tid, rt_base, ct_base, ln, quad, acc);
    __syncthreads();          // Bt readers done -> reuse Bt as fp32 LN scratch

    float (*scr)[132] = (float(*)[132])Bt;   // 64x132x4 = 33792 B <= 34816 B
    #pragma unroll
    for (int i = 0; i < 2; ++i)
        #pragma unroll
        for (int c = 0; c < 4; ++c)
            #pragma unroll
            for (int r = 0; r < 4; ++r) {
                int row = rt_base + i * 16 + quad * 4 + r;
                int col = ct_base + c * 16 + ln;
                scr[row][col] = acc[i][c][r];
            }
    __syncthreads();
    {
        int e = tid >> 2, part = tid & 3;
        float s = 0.f, q = 0.f;
        #pragma unroll
        for (int c8 = 0; c8 < 8; ++c8) {
            float4 v = *(const float4*)(&scr[e][part * 32 + c8 * 4]);
            s += v.x + v.y + v.z + v.w;
            q += v.x * v.x + v.y * v.y + v.z * v.z + v.w * v.w;
        }
        red[e][part][0] = s; red[e][part][1] = q;
    }
    __syncthreads();
    if (tid < 64) {
        float s = red[tid][0][0] + red[tid][1][0] + red[tid][2][0] + red[tid][3][0];
        float q = red[tid][0][1] + red[tid][1][1] + red[tid][2][1] + red[tid][3][1];
        float m = s * (1.0f / HD);
        float var = q * (1.0f / HD) - m * m;
        mrs[tid][0] = m;
        mrs[tid][1] = 1.0f / sqrtf(var + 1e-5f);
    }
    __syncthreads();

    // ---- Epilogue: LN scale + scatter (edge) or store (node)
    float gv[4], bv[4];
    #pragma unroll
    for (int c = 0; c < 4; ++c) {
        int col = ct_base + c * 16 + ln;
        gv[c] = g[col]; bv[c] = bln[col];
    }
    #pragma unroll
    for (int i = 0; i < 2; ++i)
        #pragma unroll
        for (int r = 0; r < 4; ++r) {
            int row = rt_base + i * 16 + quad * 4 + r;
            float m = mrs[row][0], rs = mrs[row][1];
            #pragma unroll
            for (int c = 0; c < 4; ++c) {
                int col = ct_base + c * 16 + ln;
                float v = (acc[i][c][r] - m) * rs * gv[c] + bv[c];
                if (MODE == 0) {
                    atomicAdd(&aggr_out[(size_t)dS[row] * HD + col], v);
                } else {
                    h_out[(size_t)(base + row) * HD + col] = (f16)v;
                }
            }
        }
}

// ---------------------------------------------------------------------------
// Decoder stage 1: per-channel upsample 1->4 + LN(4) + scatter-add to mesh
// ---------------------------------------------------------------------------
__global__ __launch_bounds__(128)
void dec_up_kernel(const f16* __restrict__ h, const int* __restrict__ conn,
                   const float* __restrict__ uw1, const float* __restrict__ ub1,
                   const float* __restrict__ uw2, const float* __restrict__ ub2,
                   const float* __restrict__ uw3,
                   const float* __restrict__ ulng, const float* __restrict__ ulnb,
                   float* __restrict__ outn) {
    int n = blockIdx.x;            // 0..BS*NE-1
    int b = n / NE, e = n - b * NE;
    int c = threadIdx.x;
    __shared__ int nd[4];
    if (c < 4) nd[c] = conn[e * 4 + c];
    float s = (float)h[(size_t)n * HD + c];
    float u1[4], u2[4], u3[4];
    #pragma unroll
    for (int o = 0; o < 4; ++o) u1[o] = lrelu(s * uw1[c * 4 + o] + ub1[c * 4 + o]);
    #pragma unroll
    for (int o = 0; o < 4; ++o) {
        float a = ub2[c * 4 + o];
        #pragma unroll
        for (int i = 0; i < 4; ++i) a += u1[i] * uw2[c * 16 + i * 4 + o];
        u2[o] = lrelu(a);
    }
    #pragma unroll
    for (int o = 0; o < 4; ++o) {
        float a = 0.f;
        #pragma unroll
        for (int i = 0; i < 4; ++i) a += u2[i] * uw3[c * 16 + i * 4 + o];
        u3[o] = a;
    }
    float m = 0.25f * (u3[0] + u3[1] + u3[2] + u3[3]);
    float var = 0.f;
    #pragma unroll
    for (int o = 0; o < 4; ++o) { float d = u3[o] - m; var += d * d; }
    var *= 0.25f;
    float rs = 1.0f / sqrtf(var + 1e-5f);
    __syncthreads();
    #pragma unroll
    for (int o = 0; o < 4; ++o) {
        float val = (u3[o] - m) * rs * ulng[c * 4 + o] + ulnb[c * 4 + o];
        atomicAdd(&outn[((size_t)b * NN + nd[o]) * HD + c], val);
    }
}

// ---------------------------------------------------------------------------
// Decoder stage 2: per mesh row H->3->3->3, one wave per row
// ---------------------------------------------------------------------------
__global__ __launch_bounds__(256)
void dec_out_kernel(const float* __restrict__ outn,
                    const float* __restrict__ cw1, const float* __restrict__ cb1,
                    const float* __restrict__ cw2, const float* __restrict__ cb2,
                    const float* __restrict__ cw3,
                    float* __restrict__ o, int nrows) {
    int r = blockIdx.x * 4 + (threadIdx.x >> 6);
    if (r >= nrows) return;
    int lane = threadIdx.x & 63;
    float v1 = outn[(size_t)r * HD + lane];
    float v2 = outn[(size_t)r * HD + 64 + lane];
    float s[3];
    #pragma unroll
    for (int c = 0; c < 3; ++c)
        s[c] = v1 * cw1[lane * 3 + c] + v2 * cw1[(lane + 64) * 3 + c];
    #pragma unroll
    for (int off = 32; off >= 1; off >>= 1) {
        s[0] += __shfl_down(s[0], off);
        s[1] += __shfl_down(s[1], off);
        s[2] += __shfl_down(s[2], off);
    }
    if (lane == 0) {
        float t1[3], t2[3];
        #pragma unroll
        for (int c = 0; c < 3; ++c) t1[c] = lrelu(s[c] + cb1[c]);
        #pragma unroll
        for (int c = 0; c < 3; ++c) {
            float a = cb2[c];
            #pragma unroll
            for (int k = 0; k < 3; ++k) a += t1[k] * cw2[k * 3 + c];
            t2[c] = lrelu(a);
        }
        #pragma unroll
        for (int c = 0; c < 3; ++c) {
            float a = 0.f;
            #pragma unroll
            for (int k = 0; k < 3; ++k) a += t2[k] * cw3[k * 3 + c];
            o[(size_t)r * 3 + c] = a;
        }
    }
}

// ---------------------------------------------------------------------------
extern "C" void kernel_launch(void* const* d_in, const int* in_sizes, int n_in,
                              void* d_out, int out_size, void* d_ws, size_t ws_size,
                              hipStream_t stream) {
    const int* elem_conn = (const int*)d_in[1];
    const int* edge_index = (const int*)d_in[2];
    const int* e_src = edge_index;          // row 0
    const int* e_dst = edge_index + NEDGE;  // row 1
    const float* enc_clnb = (const float*)d_in[9];
    const float* enc_ew1 = (const float*)d_in[10];
    const float* enc_eb1 = (const float*)d_in[11];
    const float* enc_ew2 = (const float*)d_in[12];
    const float* enc_eb2 = (const float*)d_in[13];
    const float* enc_ew3 = (const float*)d_in[14];
    const float* enc_elng = (const float*)d_in[15];
    const float* enc_elnb = (const float*)d_in[16];
    const float* p_ew1 = (const float*)d_in[17];
    const float* p_eb1 = (const float*)d_in[18];
    const float* p_ew2 = (const float*)d_in[19];
    const float* p_eb2 = (const float*)d_in[20];
    const float* p_ew3 = (const float*)d_in[21];
    const float* p_elng = (const float*)d_in[22];
    const float* p_elnb = (const float*)d_in[23];
    const float* p_nw1 = (const float*)d_in[24];
    const float* p_nb1 = (const float*)d_in[25];
    const float* p_nw2 = (const float*)d_in[26];
    const float* p_nb2 = (const float*)d_in[27];
    const float* p_nw3 = (const float*)d_in[28];
    const float* p_nlng = (const float*)d_in[29];
    const float* p_nlnb = (const float*)d_in[30];
    const float* dec_uw1 = (const float*)d_in[31];
    const float* dec_ub1 = (const float*)d_in[32];
    const float* dec_uw2 = (const float*)d_in[33];
    const float* dec_ub2 = (const float*)d_in[34];
    const float* dec_uw3 = (const float*)d_in[35];
    const float* dec_ulng = (const float*)d_in[36];
    const float* dec_ulnb = (const float*)d_in[37];
    const float* dec_cw1 = (const float*)d_in[38];
    const float* dec_cb1 = (const float*)d_in[39];
    const float* dec_cw2 = (const float*)d_in[40];
    const float* dec_cb2 = (const float*)d_in[41];
    const float* dec_cw3 = (const float*)d_in[42];

    // Workspace layout (bytes):
    //   hA16 (9.83 MB) | hB16 (9.83 MB) | wbuf f16 (1.5 MB) | hv0 | aggr/outn
    // aggr (fp32 NTOT*HD = 19.66 MB) and outn (fp32 NMESH*HD = 20.40 MB) share
    // one region (aggr dead before outn is first written). Total ~41.6 MB.
    char* ws = (char*)d_ws;
    f16* hA16 = (f16*)(ws);
    f16* hB16 = (f16*)(ws + 9830400);
    f16* wbuf = (f16*)(ws + 19660800);
    float* hv0 = (float*)(ws + 21233664);
    float* aggr = (float*)(ws + 21234176);
    float* outn = aggr;

    enc_const_kernel<<<1, 128, 0, stream>>>(enc_clnb, enc_ew1, enc_eb1, enc_ew2,
                                            enc_eb2, enc_ew3, enc_elng, enc_elnb, hv0);
    init_h16_kernel<<<1200, 256, 0, stream>>>(hA16, hv0, NTOT * HD / 8);
    conv_weights_kernel<<<48, 256, 0, stream>>>(p_ew1, p_ew2, p_ew3,
                                                p_nw1, p_nw2, p_nw3, wbuf);

    for (int d = 0; d < DBLK; ++d) {
        f16* cur = (d & 1) ? hB16 : hA16;
        f16* nxt = (d & 1) ? hA16 : hB16;
        const f16* ws_d = wbuf + (size_t)d * 8 * HD * HD;
        hipMemsetAsync(aggr, 0, (size_t)NTOT * HD * sizeof(float), stream);
        gn_mfma<0><<<NEDGE / 64, 256, 0, stream>>>(
            cur, nullptr, e_dst, e_src,
            ws_d + 0 * HD * HD, ws_d + 1 * HD * HD, ws_d + 2 * HD * HD, ws_d + 3 * HD * HD,
            p_eb1 + (size_t)d * HD, p_eb2 + (size_t)d * HD,
            p_elng + (size_t)d * HD, p_elnb + (size_t)d * HD,
            aggr, nullptr);
        gn_mfma<1><<<NTOT / 64, 256, 0, stream>>>(
            cur, aggr, nullptr, nullptr,
            ws_d + 4 * HD * HD, ws_d + 5 * HD * HD, ws_d + 6 * HD * HD, ws_d + 7 * HD * HD,
            p_nb1 + (size_t)d * HD, p_nb2 + (size_t)d * HD,
            p_nlng + (size_t)d * HD, p_nlnb + (size_t)d * HD,
            nullptr, nxt);
    }
    // after d=5, result is in hA16
    hipMemsetAsync(outn, 0, (size_t)NMESH * HD * sizeof(float), stream);
    dec_up_kernel<<<BS * NE, 128, 0, stream>>>(hA16, elem_conn, dec_uw1, dec_ub1,
                                               dec_uw2, dec_ub2, dec_uw3,
                                               dec_ulng, dec_ulnb, outn);
    dec_out_kernel<<<(NMESH + 3) / 4, 256, 0, stream>>>(outn, dec_cw1, dec_cb1,
                                                        dec_cw2, dec_cb2, dec_cw3,
                                                        (float*)d_out, NMESH);
}